// Round 11
// baseline (290.467 us; speedup 1.0000x reference)
//
#include <hip/hip_runtime.h>
#include <hip/hip_fp16.h>
#include <cmath>

#define D 64
#define PA_EDGES 4096     // edges per partition/bhist block
#define BSHIFT 7          // bucket = 128 nodes
#define BNODES 128
#define MAXBUCK 1024      // supports N <= 131072
#define PB_CAP 4096       // LDS csr staging per bucket (avg 2048, ~45 sigma)

typedef _Float16 hh2 __attribute__((ext_vector_type(2)));

// f32-accumulating fp16 dot2: d = a.x*b.x + a.y*b.y + c  (one VALU op).
__device__ __forceinline__ float dot2(unsigned a, unsigned b, float c) {
#if __has_builtin(__builtin_amdgcn_fdot2)
    return __builtin_amdgcn_fdot2(__builtin_bit_cast(hh2, a),
                                  __builtin_bit_cast(hh2, b), c, false);
#else
    const __half2 ah = __builtin_bit_cast(__half2, a);
    const __half2 bh = __builtin_bit_cast(__half2, b);
    const float2 af = __half22float2(ah), bf = __half22float2(bh);
    return fmaf(af.x, bf.x, fmaf(af.y, bf.y, c));
#endif
}

__device__ __forceinline__ unsigned rlu(unsigned v, int k) {
    return (unsigned)__builtin_amdgcn_readlane((int)v, k);
}

// ---------------------------------------------------------------------------
// Per-BUCKET histogram, LDS-privatized.
// ---------------------------------------------------------------------------
__global__ __launch_bounds__(256)
void bhist_kernel(const int* __restrict__ dst, int* __restrict__ bcnt, int E, int nbuck) {
    __shared__ int lh[MAXBUCK];
    const int t = threadIdx.x;
    const int e0 = blockIdx.x * PA_EDGES;
    const int ecnt = min(PA_EDGES, E - e0);
    for (int i = t; i < MAXBUCK; i += 256) lh[i] = 0;
    __syncthreads();
    for (int i = t; i < ecnt; i += 256) atomicAdd(&lh[dst[e0 + i] >> BSHIFT], 1);
    __syncthreads();
    for (int b = t; b < nbuck; b += 256) {
        const int c = lh[b];
        if (c) atomicAdd(&bcnt[b], c);
    }
}

// ---------------------------------------------------------------------------
// Exclusive scan of bucket counts -> bbase (and cursor copy). One block.
// ---------------------------------------------------------------------------
__global__ __launch_bounds__(256)
void bucket_scan_kernel(const int* __restrict__ bcnt, int* __restrict__ bbase,
                        int* __restrict__ cursor, int nbuck, int E) {
    __shared__ int red[256];
    const int t = threadIdx.x;
    const int c0 = (4 * t + 0 < nbuck) ? bcnt[4 * t + 0] : 0;
    const int c1 = (4 * t + 1 < nbuck) ? bcnt[4 * t + 1] : 0;
    const int c2 = (4 * t + 2 < nbuck) ? bcnt[4 * t + 2] : 0;
    const int c3 = (4 * t + 3 < nbuck) ? bcnt[4 * t + 3] : 0;
    red[t] = c0 + c1 + c2 + c3;
    __syncthreads();
    for (int off = 1; off < 256; off <<= 1) {
        int u = (t >= off) ? red[t - off] : 0;
        __syncthreads();
        red[t] += u;
        __syncthreads();
    }
    const int excl = (t == 0) ? 0 : red[t - 1];
    const int e0 = excl, e1 = excl + c0, e2 = excl + c0 + c1, e3 = excl + c0 + c1 + c2;
    if (4 * t + 0 <= nbuck) { bbase[4 * t + 0] = e0; }
    if (4 * t + 1 <= nbuck) { bbase[4 * t + 1] = e1; }
    if (4 * t + 2 <= nbuck) { bbase[4 * t + 2] = e2; }
    if (4 * t + 3 <= nbuck) { bbase[4 * t + 3] = e3; }
    if (4 * t + 0 < nbuck) cursor[4 * t + 0] = e0;
    if (4 * t + 1 < nbuck) cursor[4 * t + 1] = e1;
    if (4 * t + 2 < nbuck) cursor[4 * t + 2] = e2;
    if (4 * t + 3 < nbuck) cursor[4 * t + 3] = e3;
    if (t == 255) bbase[nbuck] = E;   // total (exclusive scan end)
}

// ---------------------------------------------------------------------------
// Bucket partition: (src, dst) -> packed 32-bit (src<<7 | dst&127), grouped
// by bucket (dst>>7) in `pairs`. LDS-staged; int LDS atomics only (native
// ds_add_u32 -- float LDS atomics are CAS loops on HIP, never use them).
// ---------------------------------------------------------------------------
__global__ __launch_bounds__(256)
void partition_kernel(const int* __restrict__ src, const int* __restrict__ dst,
                      int* __restrict__ cursor, unsigned* __restrict__ pairs,
                      int E, int nbuck) {
    __shared__ int lhist[MAXBUCK];            // counts, then local fill cursors
    __shared__ int lbase[MAXBUCK];            // local exclusive scan
    __shared__ int gbase[MAXBUCK];            // reserved global positions
    __shared__ int red[256];
    __shared__ unsigned stage[PA_EDGES];      // 16 KB
    __shared__ unsigned short sbuck[PA_EDGES];// 8 KB bucket id per staged slot

    const int t = threadIdx.x;
    const int e0 = blockIdx.x * PA_EDGES;
    const int ecnt = min(PA_EDGES, E - e0);

    for (int i = t; i < MAXBUCK; i += 256) lhist[i] = 0;
    __syncthreads();
    for (int i = t; i < ecnt; i += 256) atomicAdd(&lhist[dst[e0 + i] >> BSHIFT], 1);
    __syncthreads();

    // exclusive scan over 1024 entries: each thread owns 4 consecutive slots
    const int c0 = lhist[4 * t], c1 = lhist[4 * t + 1];
    const int c2 = lhist[4 * t + 2], c3 = lhist[4 * t + 3];
    red[t] = c0 + c1 + c2 + c3;
    __syncthreads();
    for (int off = 1; off < 256; off <<= 1) {
        int u = (t >= off) ? red[t - off] : 0;
        __syncthreads();
        red[t] += u;
        __syncthreads();
    }
    const int excl = (t == 0) ? 0 : red[t - 1];
    lbase[4 * t]     = excl;
    lbase[4 * t + 1] = excl + c0;
    lbase[4 * t + 2] = excl + c0 + c1;
    lbase[4 * t + 3] = excl + c0 + c1 + c2;
    for (int b = t; b < nbuck; b += 256) {
        const int c = lhist[b];
        gbase[b] = c ? atomicAdd(&cursor[b], c) : 0;
    }
    __syncthreads();
    for (int i = t; i < MAXBUCK; i += 256) lhist[i] = 0;   // reuse as fill cursors
    __syncthreads();
    for (int i = t; i < ecnt; i += 256) {
        const int d = dst[e0 + i];
        const int b = d >> BSHIFT;
        const int p = lbase[b] + atomicAdd(&lhist[b], 1);
        stage[p] = ((unsigned)src[e0 + i] << BSHIFT) | (unsigned)(d & (BNODES - 1));
        sbuck[p] = (unsigned short)b;
    }
    __syncthreads();
    for (int i = t; i < ecnt; i += 256) {
        const int b = sbuck[i];
        pairs[gbase[b] + (i - lbase[b])] = stage[i];
    }
}

// ---------------------------------------------------------------------------
// Bucket CSR fill + per-node rowStart derivation, fully on-chip.
// ---------------------------------------------------------------------------
__global__ __launch_bounds__(256)
void bucket_fill_kernel(const unsigned* __restrict__ pairs, const int* __restrict__ bbase,
                        int* __restrict__ rowStart, int* __restrict__ csr, int n, int E) {
    __shared__ int lcsr[PB_CAP];          // 16 KB
    __shared__ int lcnt[BNODES];          // per-node degree
    __shared__ int lrs[BNODES];           // per-node row start (bucket-relative)
    __shared__ int s[BNODES];             // scan workspace
    __shared__ int lfill[BNODES];
    const int t = threadIdx.x;
    const int node0 = blockIdx.x << BSHIFT;
    const int bn = min(BNODES, n - node0);
    const int base = bbase[blockIdx.x];
    const int cntE = bbase[blockIdx.x + 1] - base;

    if (t < BNODES) { lcnt[t] = 0; lfill[t] = 0; }
    __syncthreads();
    for (int i = t; i < cntE; i += 256)
        atomicAdd(&lcnt[pairs[base + i] & (BNODES - 1)], 1);
    __syncthreads();
    if (t < BNODES) s[t] = lcnt[t];
    __syncthreads();
    for (int off = 1; off < BNODES; off <<= 1) {
        int u = (t >= off && t < BNODES) ? s[t - off] : 0;
        __syncthreads();
        if (t < BNODES) s[t] += u;
        __syncthreads();
    }
    if (t < BNODES) lrs[t] = (t == 0) ? 0 : s[t - 1];
    __syncthreads();
    if (t < bn) rowStart[node0 + t] = base + lrs[t];
    if (blockIdx.x == gridDim.x - 1 && t == 0) rowStart[n] = E;

    if (cntE <= PB_CAP) {
        for (int i = t; i < cntE; i += 256) {
            const unsigned pr = pairs[base + i];
            const int dl = (int)(pr & (BNODES - 1));
            const int p = lrs[dl] + atomicAdd(&lfill[dl], 1);
            lcsr[p] = (int)(pr >> BSHIFT);
        }
        __syncthreads();
        for (int i = t; i < cntE; i += 256) csr[base + i] = lcsr[i];
    } else {   // safety fallback (statistically unreachable for random dst)
        for (int i = t; i < cntE; i += 256) {
            const unsigned pr = pairs[base + i];
            const int dl = (int)(pr & (BNODES - 1));
            const int p = base + lrs[dl] + atomicAdd(&lfill[dl], 1);
            csr[p] = (int)(pr >> BSHIFT);
        }
    }
}

// ---------------------------------------------------------------------------
// f32 -> f16 cast (vectorized, grid-stride). Dword i of a row holds halves
// (2i, 2i+1) -- the packing every fp16 consumer below assumes.
// ---------------------------------------------------------------------------
__global__ __launch_bounds__(256)
void cast_half_kernel(const float* __restrict__ in, __half* __restrict__ out, int n2) {
    const float2* in2 = (const float2*)in;
    __half2* out2 = (__half2*)out;
    int i = blockIdx.x * 256 + threadIdx.x;
    const int st = gridDim.x * 256;
    for (; i < n2; i += st) {
        const float2 v = in2[i];
        out2[i] = __floats2half2_rn(v.x, v.y);
    }
}

// ---------------------------------------------------------------------------
// Pack the 5 weight matrices to half2 k-pairs: wp[mat][p*64+j] =
// (W[2p][j], W[2p+1][j]).
// ---------------------------------------------------------------------------
__global__ __launch_bounds__(256)
void pack_w_kernel(const float* __restrict__ W1l, const float* __restrict__ W1r,
                   const float* __restrict__ W2l, const float* __restrict__ W2r,
                   const float* __restrict__ Wlin, unsigned* __restrict__ wp) {
    const int t = blockIdx.x * 256 + threadIdx.x;
    if (t >= 5 * 2048) return;
    const float* W = (t < 2048) ? W1l : (t < 4096) ? W1r : (t < 6144) ? W2l
                    : (t < 8192) ? W2r : Wlin;
    const int idx = t & 2047;
    const int p = idx >> 6, j = idx & 63;
    const __half2 h = __floats2half2_rn(W[(2 * p) * D + j], W[(2 * p + 1) * D + j]);
    wp[t] = __builtin_bit_cast(unsigned, h);
}

// ---------------------------------------------------------------------------
// FUSED SAGE LAYER: per node (one wave-iteration):
//   1. gather-mean over fp16 neighbor rows (16-lane groups, 4 rows/instr in
//      flight -- the proven aggmean structure, ~3.3 TB/s fetch-bound with
//      VALUBusy only 31%)
//   2. in-register handoff: after the shfl reductions, lane gl holds mean
//      cols 4gl..4gl+3 -> pack to half2 so dwords 2q/2q+1 live at lane q
//   3. dual dot2 matmul + ELU (the VALU work hides under other waves'
//      gather latency; weights 16-24 KB -> L1-resident)
//   FINAL=false: write h packed fp16 to hout (NOT in place of xh -- other
//   waves still gather from xh).
//   FINAL=true: chain out = h@WpF + bf in-register (h-row dword p lives at
//   even lane 2p after the shfl pack) and write f32.
// Deletes the mean-buffer round trip (2x25.6 MB/layer), the h2 round trip,
// and 3 kernel launches vs the split R10 pipeline.
// ---------------------------------------------------------------------------
__device__ __forceinline__ void addh4(float4& a, const __half* __restrict__ p) {
    union { unsigned long long u; __half2 h[2]; } r;
    r.u = *(const unsigned long long*)p;       // 8 B load
    const float2 f0 = __half22float2(r.h[0]);
    const float2 f1 = __half22float2(r.h[1]);
    a.x += f0.x; a.y += f0.y; a.z += f1.x; a.w += f1.y;
}

template <bool FINAL>
__global__ __launch_bounds__(256)
void sage_layer_kernel(const __half* __restrict__ xh,   // gather + residual src
                       const int* __restrict__ rowStart,
                       const int* __restrict__ csr,
                       const unsigned* __restrict__ WpA, // lin_l packed
                       const float* __restrict__ ba,
                       const unsigned* __restrict__ WpB, // lin_r packed
                       const unsigned* __restrict__ WpF, // Wlin packed (FINAL)
                       const float* __restrict__ bfin,   // blin (FINAL)
                       __half* __restrict__ hout,        // !FINAL
                       float* __restrict__ fout,         // FINAL
                       int n) {
    const int lane = threadIdx.x & 63;
    const int g = lane >> 4;              // group 0..3
    const int gl = lane & 15;             // lane in group
    const int wave = threadIdx.x >> 6;
    const int gw = blockIdx.x * 4 + wave;
    const int nw = gridDim.x * 4;
    const float bva = ba[lane];
    float bvf = 0.0f;
    if (FINAL) bvf = bfin[lane];

    for (int node = gw; node < n; node += nw) {
        const int r0 = rowStart[node];
        const int r1 = rowStart[node + 1];
        float4 acc0 = make_float4(0.f, 0.f, 0.f, 0.f);
        float4 acc1 = make_float4(0.f, 0.f, 0.f, 0.f);

        int j = r0;
        for (; j + 16 <= r1; j += 16) {
            const int i0 = csr[j + 0  + g];
            const int i1 = csr[j + 4  + g];
            const int i2 = csr[j + 8  + g];
            const int i3 = csr[j + 12 + g];
            addh4(acc0, &xh[(size_t)i0 * D + gl * 4]);
            addh4(acc1, &xh[(size_t)i1 * D + gl * 4]);
            addh4(acc0, &xh[(size_t)i2 * D + gl * 4]);
            addh4(acc1, &xh[(size_t)i3 * D + gl * 4]);
        }
        const int rem = r1 - j;
        if (rem > 0) {
            if (0 + g < rem) {
                const int sidx = csr[j + 0 + g];
                addh4(acc0, &xh[(size_t)sidx * D + gl * 4]);
            }
            if (4 + g < rem) {
                const int sidx = csr[j + 4 + g];
                addh4(acc1, &xh[(size_t)sidx * D + gl * 4]);
            }
            if (8 + g < rem) {
                const int sidx = csr[j + 8 + g];
                addh4(acc0, &xh[(size_t)sidx * D + gl * 4]);
            }
            if (12 + g < rem) {
                const int sidx = csr[j + 12 + g];
                addh4(acc1, &xh[(size_t)sidx * D + gl * 4]);
            }
        }

        float4 a;
        a.x = acc0.x + acc1.x; a.y = acc0.y + acc1.y;
        a.z = acc0.z + acc1.z; a.w = acc0.w + acc1.w;
        a.x += __shfl_xor(a.x, 16); a.y += __shfl_xor(a.y, 16);
        a.z += __shfl_xor(a.z, 16); a.w += __shfl_xor(a.w, 16);
        a.x += __shfl_xor(a.x, 32); a.y += __shfl_xor(a.y, 32);
        a.z += __shfl_xor(a.z, 32); a.w += __shfl_xor(a.w, 32);

        // ---- handoff: mean row packed; dwords 2q (pm0) / 2q+1 (pm1) @ lane q
        const float rdeg = 1.0f / fmaxf((float)(r1 - r0), 1.0f);
        const unsigned pm0 = __builtin_bit_cast(
            unsigned, __floats2half2_rn(a.x * rdeg, a.y * rdeg));
        const unsigned pm1 = __builtin_bit_cast(
            unsigned, __floats2half2_rn(a.z * rdeg, a.w * rdeg));
        // residual row dword per lane (dword lane&31)
        const unsigned ru = ((const unsigned*)xh)[(size_t)node * 32 + (lane & 31)];

        float o0 = bva, o1 = 0.0f, o2 = 0.0f, o3 = 0.0f;
#pragma unroll
        for (int q = 0; q < 16; q += 2) {
            o0 = dot2(rlu(pm0, q),         WpA[(2 * q + 0) * D + lane], o0);
            o0 = dot2(rlu(ru, 2 * q + 0),  WpB[(2 * q + 0) * D + lane], o0);
            o1 = dot2(rlu(pm1, q),         WpA[(2 * q + 1) * D + lane], o1);
            o1 = dot2(rlu(ru, 2 * q + 1),  WpB[(2 * q + 1) * D + lane], o1);
            o2 = dot2(rlu(pm0, q + 1),     WpA[(2 * q + 2) * D + lane], o2);
            o2 = dot2(rlu(ru, 2 * q + 2),  WpB[(2 * q + 2) * D + lane], o2);
            o3 = dot2(rlu(pm1, q + 1),     WpA[(2 * q + 3) * D + lane], o3);
            o3 = dot2(rlu(ru, 2 * q + 3),  WpB[(2 * q + 3) * D + lane], o3);
        }
        float h = (o0 + o1) + (o2 + o3);
        h = h > 0.0f ? h : expm1f(h);   // ELU(alpha=1)

        // pack h row: even lane l holds dword l/2 = cols (l, l+1)
        const float hp = __shfl_xor(h, 1);
        const unsigned ph = __builtin_bit_cast(unsigned, __floats2half2_rn(h, hp));

        if (!FINAL) {
            if (!(lane & 1))
                ((unsigned*)hout)[(size_t)node * 32 + (lane >> 1)] = ph;
        } else {
            // h-row dword p lives at lane 2p (even lanes of both half-waves ok:
            // lanes 0..62 even cover dwords 0..31)
            float f0 = bvf, f1 = 0.0f, f2 = 0.0f, f3 = 0.0f;
#pragma unroll
            for (int p = 0; p < 32; p += 4) {
                f0 = dot2(rlu(ph, 2 * (p + 0)), WpF[(p + 0) * D + lane], f0);
                f1 = dot2(rlu(ph, 2 * (p + 1)), WpF[(p + 1) * D + lane], f1);
                f2 = dot2(rlu(ph, 2 * (p + 2)), WpF[(p + 2) * D + lane], f2);
                f3 = dot2(rlu(ph, 2 * (p + 3)), WpF[(p + 3) * D + lane], f3);
            }
            fout[(size_t)node * D + lane] = (f0 + f1) + (f2 + f3);
        }
    }
}

extern "C" void kernel_launch(void* const* d_in, const int* in_sizes, int n_in,
                              void* d_out, int out_size, void* d_ws, size_t ws_size,
                              hipStream_t stream) {
    const float* x    = (const float*)d_in[0];
    const int*   ei   = (const int*)d_in[1];
    const float* W1l  = (const float*)d_in[2];
    const float* b1   = (const float*)d_in[3];
    const float* W1r  = (const float*)d_in[4];
    const float* W2l  = (const float*)d_in[5];
    const float* b2   = (const float*)d_in[6];
    const float* W2r  = (const float*)d_in[7];
    const float* Wlin = (const float*)d_in[8];
    const float* blin = (const float*)d_in[9];

    const int N_ = in_sizes[0] / D;      // 100000
    const int E_ = in_sizes[1] / 2;      // 1600000
    const int* src = ei;
    const int* dst = ei + E_;

    // workspace layout
    int* bcnt     = (int*)d_ws;                     // MAXBUCK
    int* bbase    = bcnt + MAXBUCK;                 // MAXBUCK+1
    int* cursor   = bbase + MAXBUCK + 1;            // MAXBUCK
    int* rowStart = cursor + MAXBUCK;               // N+1
    unsigned* pairs = (unsigned*)(rowStart + N_ + 1);// E (packed src<<7|dloc)
    int* csr      = (int*)(pairs + E_);             // E
    unsigned* wp  = (unsigned*)(csr + E_);          // 5*2048 packed weights
    __half* fh    = (__half*)(wp + 5 * 2048);       // N*64 halves (x, layer-1 src)
    __half* fh2   = fh + (size_t)N_ * D;            // N*64 halves (h1, layer-2 src)

    const unsigned* wp1l  = wp;
    const unsigned* wp1r  = wp + 2048;
    const unsigned* wp2l  = wp + 4096;
    const unsigned* wp2r  = wp + 6144;
    const unsigned* wplin = wp + 8192;

    const int nbuck = (N_ + BNODES - 1) >> BSHIFT;          // 782
    const int npart = (E_ + PA_EDGES - 1) / PA_EDGES;       // 391

    hipMemsetAsync(bcnt, 0, (size_t)MAXBUCK * sizeof(int), stream);

    bhist_kernel<<<npart, 256, 0, stream>>>(dst, bcnt, E_, nbuck);
    bucket_scan_kernel<<<1, 256, 0, stream>>>(bcnt, bbase, cursor, nbuck, E_);
    partition_kernel<<<npart, 256, 0, stream>>>(src, dst, cursor, pairs, E_, nbuck);
    bucket_fill_kernel<<<nbuck, 256, 0, stream>>>(pairs, bbase, rowStart, csr, N_, E_);
    cast_half_kernel<<<1024, 256, 0, stream>>>(x, fh, N_ * D / 2);
    pack_w_kernel<<<40, 256, 0, stream>>>(W1l, W1r, W2l, W2r, Wlin, wp);

    // Layer 1 (fused): h1 = ELU(mean(x[nbrs])@W1l + b1 + x@W1r)  -> fh2 (fp16)
    sage_layer_kernel<false><<<2048, 256, 0, stream>>>(
        fh, rowStart, csr, wp1l, b1, wp1r, nullptr, nullptr, fh2, nullptr, N_);
    // Layer 2 + final (fused): out = (ELU(mean(h1[nbrs])@W2l + b2 + h1@W2r))@Wlin + blin
    sage_layer_kernel<true><<<2048, 256, 0, stream>>>(
        fh2, rowStart, csr, wp2l, b2, wp2r, wplin, blin, nullptr, (float*)d_out, N_);
}

// Round 12
// 255.715 us; speedup vs baseline: 1.1359x; 1.1359x over previous
//
#include <hip/hip_runtime.h>
#include <hip/hip_fp16.h>
#include <cmath>

#define D 64
#define PA_EDGES 4096     // edges per partition/bhist block
#define BSHIFT 7          // bucket = 128 nodes
#define BNODES 128
#define MAXBUCK 1024      // supports N <= 131072
#define PB_CAP 4096       // LDS csr staging per bucket (avg 2048, ~45 sigma)

typedef _Float16 hh2 __attribute__((ext_vector_type(2)));

// f32-accumulating fp16 dot2: d = a.x*b.x + a.y*b.y + c  (one VALU op).
__device__ __forceinline__ float dot2(unsigned a, unsigned b, float c) {
#if __has_builtin(__builtin_amdgcn_fdot2)
    return __builtin_amdgcn_fdot2(__builtin_bit_cast(hh2, a),
                                  __builtin_bit_cast(hh2, b), c, false);
#else
    const __half2 ah = __builtin_bit_cast(__half2, a);
    const __half2 bh = __builtin_bit_cast(__half2, b);
    const float2 af = __half22float2(ah), bf = __half22float2(bh);
    return fmaf(af.x, bf.x, fmaf(af.y, bf.y, c));
#endif
}

__device__ __forceinline__ unsigned rlu(unsigned v, int k) {
    return (unsigned)__builtin_amdgcn_readlane((int)v, k);
}

// ---------------------------------------------------------------------------
// Per-BUCKET histogram, LDS-privatized.
// ---------------------------------------------------------------------------
__global__ __launch_bounds__(256)
void bhist_kernel(const int* __restrict__ dst, int* __restrict__ bcnt, int E, int nbuck) {
    __shared__ int lh[MAXBUCK];
    const int t = threadIdx.x;
    const int e0 = blockIdx.x * PA_EDGES;
    const int ecnt = min(PA_EDGES, E - e0);
    for (int i = t; i < MAXBUCK; i += 256) lh[i] = 0;
    __syncthreads();
    for (int i = t; i < ecnt; i += 256) atomicAdd(&lh[dst[e0 + i] >> BSHIFT], 1);
    __syncthreads();
    for (int b = t; b < nbuck; b += 256) {
        const int c = lh[b];
        if (c) atomicAdd(&bcnt[b], c);
    }
}

// ---------------------------------------------------------------------------
// Exclusive scan of bucket counts -> bbase (and cursor copy). One block.
// ---------------------------------------------------------------------------
__global__ __launch_bounds__(256)
void bucket_scan_kernel(const int* __restrict__ bcnt, int* __restrict__ bbase,
                        int* __restrict__ cursor, int nbuck, int E) {
    __shared__ int red[256];
    const int t = threadIdx.x;
    const int c0 = (4 * t + 0 < nbuck) ? bcnt[4 * t + 0] : 0;
    const int c1 = (4 * t + 1 < nbuck) ? bcnt[4 * t + 1] : 0;
    const int c2 = (4 * t + 2 < nbuck) ? bcnt[4 * t + 2] : 0;
    const int c3 = (4 * t + 3 < nbuck) ? bcnt[4 * t + 3] : 0;
    red[t] = c0 + c1 + c2 + c3;
    __syncthreads();
    for (int off = 1; off < 256; off <<= 1) {
        int u = (t >= off) ? red[t - off] : 0;
        __syncthreads();
        red[t] += u;
        __syncthreads();
    }
    const int excl = (t == 0) ? 0 : red[t - 1];
    const int e0 = excl, e1 = excl + c0, e2 = excl + c0 + c1, e3 = excl + c0 + c1 + c2;
    if (4 * t + 0 <= nbuck) { bbase[4 * t + 0] = e0; }
    if (4 * t + 1 <= nbuck) { bbase[4 * t + 1] = e1; }
    if (4 * t + 2 <= nbuck) { bbase[4 * t + 2] = e2; }
    if (4 * t + 3 <= nbuck) { bbase[4 * t + 3] = e3; }
    if (4 * t + 0 < nbuck) cursor[4 * t + 0] = e0;
    if (4 * t + 1 < nbuck) cursor[4 * t + 1] = e1;
    if (4 * t + 2 < nbuck) cursor[4 * t + 2] = e2;
    if (4 * t + 3 < nbuck) cursor[4 * t + 3] = e3;
    if (t == 255) bbase[nbuck] = E;   // total (exclusive scan end)
}

// ---------------------------------------------------------------------------
// Bucket partition: (src, dst) -> packed 32-bit (src<<7 | dst&127), grouped
// by bucket (dst>>7) in `pairs`. LDS-staged; int LDS atomics only (native
// ds_add_u32 -- float LDS atomics are CAS loops on HIP, never use them).
// ---------------------------------------------------------------------------
__global__ __launch_bounds__(256)
void partition_kernel(const int* __restrict__ src, const int* __restrict__ dst,
                      int* __restrict__ cursor, unsigned* __restrict__ pairs,
                      int E, int nbuck) {
    __shared__ int lhist[MAXBUCK];            // counts, then local fill cursors
    __shared__ int lbase[MAXBUCK];            // local exclusive scan
    __shared__ int gbase[MAXBUCK];            // reserved global positions
    __shared__ int red[256];
    __shared__ unsigned stage[PA_EDGES];      // 16 KB
    __shared__ unsigned short sbuck[PA_EDGES];// 8 KB bucket id per staged slot

    const int t = threadIdx.x;
    const int e0 = blockIdx.x * PA_EDGES;
    const int ecnt = min(PA_EDGES, E - e0);

    for (int i = t; i < MAXBUCK; i += 256) lhist[i] = 0;
    __syncthreads();
    for (int i = t; i < ecnt; i += 256) atomicAdd(&lhist[dst[e0 + i] >> BSHIFT], 1);
    __syncthreads();

    // exclusive scan over 1024 entries: each thread owns 4 consecutive slots
    const int c0 = lhist[4 * t], c1 = lhist[4 * t + 1];
    const int c2 = lhist[4 * t + 2], c3 = lhist[4 * t + 3];
    red[t] = c0 + c1 + c2 + c3;
    __syncthreads();
    for (int off = 1; off < 256; off <<= 1) {
        int u = (t >= off) ? red[t - off] : 0;
        __syncthreads();
        red[t] += u;
        __syncthreads();
    }
    const int excl = (t == 0) ? 0 : red[t - 1];
    lbase[4 * t]     = excl;
    lbase[4 * t + 1] = excl + c0;
    lbase[4 * t + 2] = excl + c0 + c1;
    lbase[4 * t + 3] = excl + c0 + c1 + c2;
    for (int b = t; b < nbuck; b += 256) {
        const int c = lhist[b];
        gbase[b] = c ? atomicAdd(&cursor[b], c) : 0;
    }
    __syncthreads();
    for (int i = t; i < MAXBUCK; i += 256) lhist[i] = 0;   // reuse as fill cursors
    __syncthreads();
    for (int i = t; i < ecnt; i += 256) {
        const int d = dst[e0 + i];
        const int b = d >> BSHIFT;
        const int p = lbase[b] + atomicAdd(&lhist[b], 1);
        stage[p] = ((unsigned)src[e0 + i] << BSHIFT) | (unsigned)(d & (BNODES - 1));
        sbuck[p] = (unsigned short)b;
    }
    __syncthreads();
    for (int i = t; i < ecnt; i += 256) {
        const int b = sbuck[i];
        pairs[gbase[b] + (i - lbase[b])] = stage[i];
    }
}

// ---------------------------------------------------------------------------
// Bucket CSR fill + per-node rowStart derivation, fully on-chip.
// ---------------------------------------------------------------------------
__global__ __launch_bounds__(256)
void bucket_fill_kernel(const unsigned* __restrict__ pairs, const int* __restrict__ bbase,
                        int* __restrict__ rowStart, int* __restrict__ csr, int n, int E) {
    __shared__ int lcsr[PB_CAP];          // 16 KB
    __shared__ int lcnt[BNODES];          // per-node degree
    __shared__ int lrs[BNODES];           // per-node row start (bucket-relative)
    __shared__ int s[BNODES];             // scan workspace
    __shared__ int lfill[BNODES];
    const int t = threadIdx.x;
    const int node0 = blockIdx.x << BSHIFT;
    const int bn = min(BNODES, n - node0);
    const int base = bbase[blockIdx.x];
    const int cntE = bbase[blockIdx.x + 1] - base;

    if (t < BNODES) { lcnt[t] = 0; lfill[t] = 0; }
    __syncthreads();
    for (int i = t; i < cntE; i += 256)
        atomicAdd(&lcnt[pairs[base + i] & (BNODES - 1)], 1);
    __syncthreads();
    if (t < BNODES) s[t] = lcnt[t];
    __syncthreads();
    for (int off = 1; off < BNODES; off <<= 1) {
        int u = (t >= off && t < BNODES) ? s[t - off] : 0;
        __syncthreads();
        if (t < BNODES) s[t] += u;
        __syncthreads();
    }
    if (t < BNODES) lrs[t] = (t == 0) ? 0 : s[t - 1];
    __syncthreads();
    if (t < bn) rowStart[node0 + t] = base + lrs[t];
    if (blockIdx.x == gridDim.x - 1 && t == 0) rowStart[n] = E;

    if (cntE <= PB_CAP) {
        for (int i = t; i < cntE; i += 256) {
            const unsigned pr = pairs[base + i];
            const int dl = (int)(pr & (BNODES - 1));
            const int p = lrs[dl] + atomicAdd(&lfill[dl], 1);
            lcsr[p] = (int)(pr >> BSHIFT);
        }
        __syncthreads();
        for (int i = t; i < cntE; i += 256) csr[base + i] = lcsr[i];
    } else {   // safety fallback (statistically unreachable for random dst)
        for (int i = t; i < cntE; i += 256) {
            const unsigned pr = pairs[base + i];
            const int dl = (int)(pr & (BNODES - 1));
            const int p = base + lrs[dl] + atomicAdd(&lfill[dl], 1);
            csr[p] = (int)(pr >> BSHIFT);
        }
    }
}

// ---------------------------------------------------------------------------
// f32 -> f16 cast (vectorized, grid-stride). Dword i of a row holds halves
// (2i, 2i+1) -- the packing every fp16 consumer below assumes.
// ---------------------------------------------------------------------------
__global__ __launch_bounds__(256)
void cast_half_kernel(const float* __restrict__ in, __half* __restrict__ out, int n2) {
    const float2* in2 = (const float2*)in;
    __half2* out2 = (__half2*)out;
    int i = blockIdx.x * 256 + threadIdx.x;
    const int st = gridDim.x * 256;
    for (; i < n2; i += st) {
        const float2 v = in2[i];
        out2[i] = __floats2half2_rn(v.x, v.y);
    }
}

// ---------------------------------------------------------------------------
// Pack the 5 weight matrices to half2 k-pairs: wp[mat][p*64+j] =
// (W[2p][j], W[2p+1][j]).
// ---------------------------------------------------------------------------
__global__ __launch_bounds__(256)
void pack_w_kernel(const float* __restrict__ W1l, const float* __restrict__ W1r,
                   const float* __restrict__ W2l, const float* __restrict__ W2r,
                   const float* __restrict__ Wlin, unsigned* __restrict__ wp) {
    const int t = blockIdx.x * 256 + threadIdx.x;
    if (t >= 5 * 2048) return;
    const float* W = (t < 2048) ? W1l : (t < 4096) ? W1r : (t < 6144) ? W2l
                    : (t < 8192) ? W2r : Wlin;
    const int idx = t & 2047;
    const int p = idx >> 6, j = idx & 63;
    const __half2 h = __floats2half2_rn(W[(2 * p) * D + j], W[(2 * p + 1) * D + j]);
    wp[t] = __builtin_bit_cast(unsigned, h);
}

// ---------------------------------------------------------------------------
// Gather-mean from the fp16 feature copy; output packed fp16. This kernel
// stays REGISTER-LEAN (VGPR 20, 70% occupancy) -- R11 proved that fusing
// the transform in here collapses occupancy and with it the ~3.3 TB/s
// random-gather throughput. Keep it memory-only.
// ---------------------------------------------------------------------------
__device__ __forceinline__ void addh4(float4& a, const __half* __restrict__ p) {
    union { unsigned long long u; __half2 h[2]; } r;
    r.u = *(const unsigned long long*)p;       // 8 B load
    const float2 f0 = __half22float2(r.h[0]);
    const float2 f1 = __half22float2(r.h[1]);
    a.x += f0.x; a.y += f0.y; a.z += f1.x; a.w += f1.y;
}

__global__ __launch_bounds__(256)
void aggmean_kernel(const __half* __restrict__ xh, const int* __restrict__ rowStart,
                    const int* __restrict__ csr, __half* __restrict__ m, int n) {
    const int lane = threadIdx.x & 63;
    const int g = lane >> 4;              // group 0..3
    const int gl = lane & 15;             // lane in group
    const int wave = threadIdx.x >> 6;
    const int gw = blockIdx.x * 4 + wave;
    const int nw = gridDim.x * 4;

    for (int node = gw; node < n; node += nw) {
        const int r0 = rowStart[node];
        const int r1 = rowStart[node + 1];
        float4 acc0 = make_float4(0.f, 0.f, 0.f, 0.f);
        float4 acc1 = make_float4(0.f, 0.f, 0.f, 0.f);

        int j = r0;
        for (; j + 16 <= r1; j += 16) {
            const int i0 = csr[j + 0  + g];
            const int i1 = csr[j + 4  + g];
            const int i2 = csr[j + 8  + g];
            const int i3 = csr[j + 12 + g];
            addh4(acc0, &xh[(size_t)i0 * D + gl * 4]);
            addh4(acc1, &xh[(size_t)i1 * D + gl * 4]);
            addh4(acc0, &xh[(size_t)i2 * D + gl * 4]);
            addh4(acc1, &xh[(size_t)i3 * D + gl * 4]);
        }
        const int rem = r1 - j;
        if (rem > 0) {
            if (0 + g < rem) {
                const int sidx = csr[j + 0 + g];
                addh4(acc0, &xh[(size_t)sidx * D + gl * 4]);
            }
            if (4 + g < rem) {
                const int sidx = csr[j + 4 + g];
                addh4(acc1, &xh[(size_t)sidx * D + gl * 4]);
            }
            if (8 + g < rem) {
                const int sidx = csr[j + 8 + g];
                addh4(acc0, &xh[(size_t)sidx * D + gl * 4]);
            }
            if (12 + g < rem) {
                const int sidx = csr[j + 12 + g];
                addh4(acc1, &xh[(size_t)sidx * D + gl * 4]);
            }
        }

        float4 a;
        a.x = acc0.x + acc1.x; a.y = acc0.y + acc1.y;
        a.z = acc0.z + acc1.z; a.w = acc0.w + acc1.w;
        a.x += __shfl_xor(a.x, 16); a.y += __shfl_xor(a.y, 16);
        a.z += __shfl_xor(a.z, 16); a.w += __shfl_xor(a.w, 16);
        a.x += __shfl_xor(a.x, 32); a.y += __shfl_xor(a.y, 32);
        a.z += __shfl_xor(a.z, 32); a.w += __shfl_xor(a.w, 32);

        if (lane < 16) {
            const float rdeg = 1.0f / fmaxf((float)(r1 - r0), 1.0f);
            const __half2 p0 = __floats2half2_rn(a.x * rdeg, a.y * rdeg);
            const __half2 p1 = __floats2half2_rn(a.z * rdeg, a.w * rdeg);
            uint2 o = make_uint2(__builtin_bit_cast(unsigned, p0),
                                 __builtin_bit_cast(unsigned, p1));
            ((uint2*)m)[(size_t)node * 16 + gl] = o;
        }
    }
}

// ---------------------------------------------------------------------------
// Fused SAGE transform (fp16 dot2): h = ELU(m@Wa + ba + res@Wb).
// FINAL=false: write h packed fp16 (in place of res is safe: own-row only).
// FINAL=true: chain out = h@WpF + bfin in-register (h-row dword p lives at
// even lane 2p after the shfl pack -- logic verified in R11) and write f32.
// Deletes the separate final_mm pass (12.8 MB re-read + launch).
// ---------------------------------------------------------------------------
template <bool FINAL>
__global__ __launch_bounds__(256)
void fused_mm_kernel(const __half* __restrict__ m,
                     const __half* __restrict__ res,
                     const unsigned* __restrict__ WpA,
                     const float* __restrict__ ba,
                     const unsigned* __restrict__ WpB,
                     const unsigned* __restrict__ WpF,  // FINAL only
                     const float* __restrict__ bfin,    // FINAL only
                     __half* __restrict__ hout,         // !FINAL
                     float* __restrict__ fout,          // FINAL
                     int n) {
    const int lane = threadIdx.x & 63;
    const int wave = threadIdx.x >> 6;
    const int gw = blockIdx.x * 4 + wave;
    const int nw = gridDim.x * 4;
    const float bva = ba[lane];
    float bvf = 0.0f;
    if (FINAL) bvf = bfin[lane];

    for (int node = gw; node < n; node += nw) {
        const unsigned mu = ((const unsigned*)m)[(size_t)node * 32 + (lane & 31)];
        const unsigned ru = ((const unsigned*)res)[(size_t)node * 32 + (lane & 31)];
        float o0 = bva, o1 = 0.0f, o2 = 0.0f, o3 = 0.0f;
#pragma unroll
        for (int p = 0; p < 32; p += 4) {
            o0 = dot2(rlu(mu, p + 0), WpA[(p + 0) * D + lane], o0);
            o0 = dot2(rlu(ru, p + 0), WpB[(p + 0) * D + lane], o0);
            o1 = dot2(rlu(mu, p + 1), WpA[(p + 1) * D + lane], o1);
            o1 = dot2(rlu(ru, p + 1), WpB[(p + 1) * D + lane], o1);
            o2 = dot2(rlu(mu, p + 2), WpA[(p + 2) * D + lane], o2);
            o2 = dot2(rlu(ru, p + 2), WpB[(p + 2) * D + lane], o2);
            o3 = dot2(rlu(mu, p + 3), WpA[(p + 3) * D + lane], o3);
            o3 = dot2(rlu(ru, p + 3), WpB[(p + 3) * D + lane], o3);
        }
        float h = (o0 + o1) + (o2 + o3);
        h = h > 0.0f ? h : expm1f(h);   // ELU(alpha=1)

        // pack h row: even lane l holds dword l/2 = cols (l, l+1)
        const float hp = __shfl_xor(h, 1);
        const unsigned ph = __builtin_bit_cast(unsigned, __floats2half2_rn(h, hp));

        if (!FINAL) {
            if (!(lane & 1))
                ((unsigned*)hout)[(size_t)node * 32 + (lane >> 1)] = ph;
        } else {
            float f0 = bvf, f1 = 0.0f, f2 = 0.0f, f3 = 0.0f;
#pragma unroll
            for (int p = 0; p < 32; p += 4) {
                f0 = dot2(rlu(ph, 2 * (p + 0)), WpF[(p + 0) * D + lane], f0);
                f1 = dot2(rlu(ph, 2 * (p + 1)), WpF[(p + 1) * D + lane], f1);
                f2 = dot2(rlu(ph, 2 * (p + 2)), WpF[(p + 2) * D + lane], f2);
                f3 = dot2(rlu(ph, 2 * (p + 3)), WpF[(p + 3) * D + lane], f3);
            }
            fout[(size_t)node * D + lane] = (f0 + f1) + (f2 + f3);
        }
    }
}

extern "C" void kernel_launch(void* const* d_in, const int* in_sizes, int n_in,
                              void* d_out, int out_size, void* d_ws, size_t ws_size,
                              hipStream_t stream) {
    const float* x    = (const float*)d_in[0];
    const int*   ei   = (const int*)d_in[1];
    const float* W1l  = (const float*)d_in[2];
    const float* b1   = (const float*)d_in[3];
    const float* W1r  = (const float*)d_in[4];
    const float* W2l  = (const float*)d_in[5];
    const float* b2   = (const float*)d_in[6];
    const float* W2r  = (const float*)d_in[7];
    const float* Wlin = (const float*)d_in[8];
    const float* blin = (const float*)d_in[9];

    const int N_ = in_sizes[0] / D;      // 100000
    const int E_ = in_sizes[1] / 2;      // 1600000
    const int* src = ei;
    const int* dst = ei + E_;

    // workspace layout
    int* bcnt     = (int*)d_ws;                     // MAXBUCK
    int* bbase    = bcnt + MAXBUCK;                 // MAXBUCK+1
    int* cursor   = bbase + MAXBUCK + 1;            // MAXBUCK
    int* rowStart = cursor + MAXBUCK;               // N+1
    unsigned* pairs = (unsigned*)(rowStart + N_ + 1);// E (packed src<<7|dloc)
    int* csr      = (int*)(pairs + E_);             // E
    unsigned* wp  = (unsigned*)(csr + E_);          // 5*2048 packed weights
    __half* mh    = (__half*)(wp + 5 * 2048);       // N*64 halves (mean, packed)
    __half* fh    = mh + (size_t)N_ * D;            // N*64 halves (x -> h1 -> h2)

    const unsigned* wp1l  = wp;
    const unsigned* wp1r  = wp + 2048;
    const unsigned* wp2l  = wp + 4096;
    const unsigned* wp2r  = wp + 6144;
    const unsigned* wplin = wp + 8192;

    const int nbuck = (N_ + BNODES - 1) >> BSHIFT;          // 782
    const int npart = (E_ + PA_EDGES - 1) / PA_EDGES;       // 391

    hipMemsetAsync(bcnt, 0, (size_t)MAXBUCK * sizeof(int), stream);

    bhist_kernel<<<npart, 256, 0, stream>>>(dst, bcnt, E_, nbuck);
    bucket_scan_kernel<<<1, 256, 0, stream>>>(bcnt, bbase, cursor, nbuck, E_);
    partition_kernel<<<npart, 256, 0, stream>>>(src, dst, cursor, pairs, E_, nbuck);
    bucket_fill_kernel<<<nbuck, 256, 0, stream>>>(pairs, bbase, rowStart, csr, N_, E_);
    cast_half_kernel<<<1024, 256, 0, stream>>>(x, fh, N_ * D / 2);
    pack_w_kernel<<<40, 256, 0, stream>>>(W1l, W1r, W2l, W2r, Wlin, wp);

    // Layer 1: m1 = mean(xh[nbrs]) ; h1 = ELU(m1@W1l + b1 + x@W1r)  -> fh (fp16)
    aggmean_kernel<<<2048, 256, 0, stream>>>(fh, rowStart, csr, mh, N_);
    fused_mm_kernel<false><<<2048, 256, 0, stream>>>(
        mh, fh, wp1l, b1, wp1r, nullptr, nullptr, fh, nullptr, N_);
    // Layer 2: m2 = mean(h1[nbrs]) ; out = ELU(m2@W2l + b2 + h1@W2r)@Wlin + blin
    aggmean_kernel<<<2048, 256, 0, stream>>>(fh, rowStart, csr, mh, N_);
    fused_mm_kernel<true><<<2048, 256, 0, stream>>>(
        mh, fh, wp2l, b2, wp2r, wplin, blin, nullptr, (float*)d_out, N_);
}

// Round 13
// 209.009 us; speedup vs baseline: 1.3897x; 1.2235x over previous
//
#include <hip/hip_runtime.h>
#include <hip/hip_fp16.h>
#include <cmath>

#define D 64
#define PA_EDGES 4096     // edges per partition/bhist block
#define BSHIFT 7          // bucket = 128 nodes
#define BNODES 128
#define MAXBUCK 1024      // supports N <= 131072
#define PB_CAP 4096       // LDS csr staging per bucket (avg 2048, ~45 sigma)

typedef _Float16 f16x8 __attribute__((ext_vector_type(8)));
typedef float f32x4 __attribute__((ext_vector_type(4)));

// ---------------------------------------------------------------------------
// Per-BUCKET histogram, LDS-privatized.
// ---------------------------------------------------------------------------
__global__ __launch_bounds__(256)
void bhist_kernel(const int* __restrict__ dst, int* __restrict__ bcnt, int E, int nbuck) {
    __shared__ int lh[MAXBUCK];
    const int t = threadIdx.x;
    const int e0 = blockIdx.x * PA_EDGES;
    const int ecnt = min(PA_EDGES, E - e0);
    for (int i = t; i < MAXBUCK; i += 256) lh[i] = 0;
    __syncthreads();
    for (int i = t; i < ecnt; i += 256) atomicAdd(&lh[dst[e0 + i] >> BSHIFT], 1);
    __syncthreads();
    for (int b = t; b < nbuck; b += 256) {
        const int c = lh[b];
        if (c) atomicAdd(&bcnt[b], c);
    }
}

// ---------------------------------------------------------------------------
// Exclusive scan of bucket counts -> bbase (and cursor copy). One block.
// ---------------------------------------------------------------------------
__global__ __launch_bounds__(256)
void bucket_scan_kernel(const int* __restrict__ bcnt, int* __restrict__ bbase,
                        int* __restrict__ cursor, int nbuck, int E) {
    __shared__ int red[256];
    const int t = threadIdx.x;
    const int c0 = (4 * t + 0 < nbuck) ? bcnt[4 * t + 0] : 0;
    const int c1 = (4 * t + 1 < nbuck) ? bcnt[4 * t + 1] : 0;
    const int c2 = (4 * t + 2 < nbuck) ? bcnt[4 * t + 2] : 0;
    const int c3 = (4 * t + 3 < nbuck) ? bcnt[4 * t + 3] : 0;
    red[t] = c0 + c1 + c2 + c3;
    __syncthreads();
    for (int off = 1; off < 256; off <<= 1) {
        int u = (t >= off) ? red[t - off] : 0;
        __syncthreads();
        red[t] += u;
        __syncthreads();
    }
    const int excl = (t == 0) ? 0 : red[t - 1];
    const int e0 = excl, e1 = excl + c0, e2 = excl + c0 + c1, e3 = excl + c0 + c1 + c2;
    if (4 * t + 0 <= nbuck) { bbase[4 * t + 0] = e0; }
    if (4 * t + 1 <= nbuck) { bbase[4 * t + 1] = e1; }
    if (4 * t + 2 <= nbuck) { bbase[4 * t + 2] = e2; }
    if (4 * t + 3 <= nbuck) { bbase[4 * t + 3] = e3; }
    if (4 * t + 0 < nbuck) cursor[4 * t + 0] = e0;
    if (4 * t + 1 < nbuck) cursor[4 * t + 1] = e1;
    if (4 * t + 2 < nbuck) cursor[4 * t + 2] = e2;
    if (4 * t + 3 < nbuck) cursor[4 * t + 3] = e3;
    if (t == 255) bbase[nbuck] = E;   // total (exclusive scan end)
}

// ---------------------------------------------------------------------------
// Bucket partition: (src, dst) -> packed 32-bit (src<<7 | dst&127), grouped
// by bucket (dst>>7) in `pairs`. LDS-staged; int LDS atomics only (native
// ds_add_u32 -- float LDS atomics are CAS loops on HIP, never use them).
// ---------------------------------------------------------------------------
__global__ __launch_bounds__(256)
void partition_kernel(const int* __restrict__ src, const int* __restrict__ dst,
                      int* __restrict__ cursor, unsigned* __restrict__ pairs,
                      int E, int nbuck) {
    __shared__ int lhist[MAXBUCK];            // counts, then local fill cursors
    __shared__ int lbase[MAXBUCK];            // local exclusive scan
    __shared__ int gbase[MAXBUCK];            // reserved global positions
    __shared__ int red[256];
    __shared__ unsigned stage[PA_EDGES];      // 16 KB
    __shared__ unsigned short sbuck[PA_EDGES];// 8 KB bucket id per staged slot

    const int t = threadIdx.x;
    const int e0 = blockIdx.x * PA_EDGES;
    const int ecnt = min(PA_EDGES, E - e0);

    for (int i = t; i < MAXBUCK; i += 256) lhist[i] = 0;
    __syncthreads();
    for (int i = t; i < ecnt; i += 256) atomicAdd(&lhist[dst[e0 + i] >> BSHIFT], 1);
    __syncthreads();

    // exclusive scan over 1024 entries: each thread owns 4 consecutive slots
    const int c0 = lhist[4 * t], c1 = lhist[4 * t + 1];
    const int c2 = lhist[4 * t + 2], c3 = lhist[4 * t + 3];
    red[t] = c0 + c1 + c2 + c3;
    __syncthreads();
    for (int off = 1; off < 256; off <<= 1) {
        int u = (t >= off) ? red[t - off] : 0;
        __syncthreads();
        red[t] += u;
        __syncthreads();
    }
    const int excl = (t == 0) ? 0 : red[t - 1];
    lbase[4 * t]     = excl;
    lbase[4 * t + 1] = excl + c0;
    lbase[4 * t + 2] = excl + c0 + c1;
    lbase[4 * t + 3] = excl + c0 + c1 + c2;
    for (int b = t; b < nbuck; b += 256) {
        const int c = lhist[b];
        gbase[b] = c ? atomicAdd(&cursor[b], c) : 0;
    }
    __syncthreads();
    for (int i = t; i < MAXBUCK; i += 256) lhist[i] = 0;   // reuse as fill cursors
    __syncthreads();
    for (int i = t; i < ecnt; i += 256) {
        const int d = dst[e0 + i];
        const int b = d >> BSHIFT;
        const int p = lbase[b] + atomicAdd(&lhist[b], 1);
        stage[p] = ((unsigned)src[e0 + i] << BSHIFT) | (unsigned)(d & (BNODES - 1));
        sbuck[p] = (unsigned short)b;
    }
    __syncthreads();
    for (int i = t; i < ecnt; i += 256) {
        const int b = sbuck[i];
        pairs[gbase[b] + (i - lbase[b])] = stage[i];
    }
}

// ---------------------------------------------------------------------------
// Bucket CSR fill + per-node rowStart derivation, fully on-chip.
// ---------------------------------------------------------------------------
__global__ __launch_bounds__(256)
void bucket_fill_kernel(const unsigned* __restrict__ pairs, const int* __restrict__ bbase,
                        int* __restrict__ rowStart, int* __restrict__ csr, int n, int E) {
    __shared__ int lcsr[PB_CAP];          // 16 KB
    __shared__ int lcnt[BNODES];          // per-node degree
    __shared__ int lrs[BNODES];           // per-node row start (bucket-relative)
    __shared__ int s[BNODES];             // scan workspace
    __shared__ int lfill[BNODES];
    const int t = threadIdx.x;
    const int node0 = blockIdx.x << BSHIFT;
    const int bn = min(BNODES, n - node0);
    const int base = bbase[blockIdx.x];
    const int cntE = bbase[blockIdx.x + 1] - base;

    if (t < BNODES) { lcnt[t] = 0; lfill[t] = 0; }
    __syncthreads();
    for (int i = t; i < cntE; i += 256)
        atomicAdd(&lcnt[pairs[base + i] & (BNODES - 1)], 1);
    __syncthreads();
    if (t < BNODES) s[t] = lcnt[t];
    __syncthreads();
    for (int off = 1; off < BNODES; off <<= 1) {
        int u = (t >= off && t < BNODES) ? s[t - off] : 0;
        __syncthreads();
        if (t < BNODES) s[t] += u;
        __syncthreads();
    }
    if (t < BNODES) lrs[t] = (t == 0) ? 0 : s[t - 1];
    __syncthreads();
    if (t < bn) rowStart[node0 + t] = base + lrs[t];
    if (blockIdx.x == gridDim.x - 1 && t == 0) rowStart[n] = E;

    if (cntE <= PB_CAP) {
        for (int i = t; i < cntE; i += 256) {
            const unsigned pr = pairs[base + i];
            const int dl = (int)(pr & (BNODES - 1));
            const int p = lrs[dl] + atomicAdd(&lfill[dl], 1);
            lcsr[p] = (int)(pr >> BSHIFT);
        }
        __syncthreads();
        for (int i = t; i < cntE; i += 256) csr[base + i] = lcsr[i];
    } else {   // safety fallback (statistically unreachable for random dst)
        for (int i = t; i < cntE; i += 256) {
            const unsigned pr = pairs[base + i];
            const int dl = (int)(pr & (BNODES - 1));
            const int p = base + lrs[dl] + atomicAdd(&lfill[dl], 1);
            csr[p] = (int)(pr >> BSHIFT);
        }
    }
}

// ---------------------------------------------------------------------------
// f32 -> f16 cast (vectorized, grid-stride). Row-major halves.
// ---------------------------------------------------------------------------
__global__ __launch_bounds__(256)
void cast_half_kernel(const float* __restrict__ in, __half* __restrict__ out, int n2) {
    const float2* in2 = (const float2*)in;
    __half2* out2 = (__half2*)out;
    int i = blockIdx.x * 256 + threadIdx.x;
    const int st = gridDim.x * 256;
    for (; i < n2; i += st) {
        const float2 v = in2[i];
        out2[i] = __floats2half2_rn(v.x, v.y);
    }
}

// ---------------------------------------------------------------------------
// Pack the 5 weight matrices into MFMA B-fragment order (fp16):
// wB[mat][((c*2+kk)*64 + lane)*8 + e] = W[kk*32 + (lane>>4)*8 + e][c*16 + (lane&15)]
// so one 16B lane-load delivers a ready B-fragment for col-tile c, K-step kk.
// ---------------------------------------------------------------------------
__global__ __launch_bounds__(256)
void pack_wb_kernel(const float* __restrict__ W1l, const float* __restrict__ W1r,
                    const float* __restrict__ W2l, const float* __restrict__ W2r,
                    const float* __restrict__ Wlin, __half* __restrict__ wB) {
    const int t = blockIdx.x * 256 + threadIdx.x;
    if (t >= 5 * 4096) return;
    const int mat = t >> 12;
    const float* W = (mat == 0) ? W1l : (mat == 1) ? W1r : (mat == 2) ? W2l
                    : (mat == 3) ? W2r : Wlin;
    const int r = t & 4095;
    const int e = r & 7;
    const int ln = (r >> 3) & 63;
    const int kk = (r >> 9) & 1;
    const int c = r >> 10;
    const int k = kk * 32 + ((ln >> 4) << 3) + e;
    const int col = c * 16 + (ln & 15);
    wB[t] = __float2half_rn(W[k * D + col]);
}

// ---------------------------------------------------------------------------
// Gather-mean from the fp16 feature copy; output packed fp16 row-major.
// REGISTER-LEAN (VGPR 20, 70% occupancy) -- R11 proved fusing compute here
// collapses occupancy and the ~3.3 TB/s random-gather throughput.
// ---------------------------------------------------------------------------
__device__ __forceinline__ void addh4(float4& a, const __half* __restrict__ p) {
    union { unsigned long long u; __half2 h[2]; } r;
    r.u = *(const unsigned long long*)p;       // 8 B load
    const float2 f0 = __half22float2(r.h[0]);
    const float2 f1 = __half22float2(r.h[1]);
    a.x += f0.x; a.y += f0.y; a.z += f1.x; a.w += f1.y;
}

__global__ __launch_bounds__(256)
void aggmean_kernel(const __half* __restrict__ xh, const int* __restrict__ rowStart,
                    const int* __restrict__ csr, __half* __restrict__ m, int n) {
    const int lane = threadIdx.x & 63;
    const int g = lane >> 4;              // group 0..3
    const int gl = lane & 15;             // lane in group
    const int wave = threadIdx.x >> 6;
    const int gw = blockIdx.x * 4 + wave;
    const int nw = gridDim.x * 4;

    for (int node = gw; node < n; node += nw) {
        const int r0 = rowStart[node];
        const int r1 = rowStart[node + 1];
        float4 acc0 = make_float4(0.f, 0.f, 0.f, 0.f);
        float4 acc1 = make_float4(0.f, 0.f, 0.f, 0.f);

        int j = r0;
        for (; j + 16 <= r1; j += 16) {
            const int i0 = csr[j + 0  + g];
            const int i1 = csr[j + 4  + g];
            const int i2 = csr[j + 8  + g];
            const int i3 = csr[j + 12 + g];
            addh4(acc0, &xh[(size_t)i0 * D + gl * 4]);
            addh4(acc1, &xh[(size_t)i1 * D + gl * 4]);
            addh4(acc0, &xh[(size_t)i2 * D + gl * 4]);
            addh4(acc1, &xh[(size_t)i3 * D + gl * 4]);
        }
        const int rem = r1 - j;
        if (rem > 0) {
            if (0 + g < rem) {
                const int sidx = csr[j + 0 + g];
                addh4(acc0, &xh[(size_t)sidx * D + gl * 4]);
            }
            if (4 + g < rem) {
                const int sidx = csr[j + 4 + g];
                addh4(acc1, &xh[(size_t)sidx * D + gl * 4]);
            }
            if (8 + g < rem) {
                const int sidx = csr[j + 8 + g];
                addh4(acc0, &xh[(size_t)sidx * D + gl * 4]);
            }
            if (12 + g < rem) {
                const int sidx = csr[j + 12 + g];
                addh4(acc1, &xh[(size_t)sidx * D + gl * 4]);
            }
        }

        float4 a;
        a.x = acc0.x + acc1.x; a.y = acc0.y + acc1.y;
        a.z = acc0.z + acc1.z; a.w = acc0.w + acc1.w;
        a.x += __shfl_xor(a.x, 16); a.y += __shfl_xor(a.y, 16);
        a.z += __shfl_xor(a.z, 16); a.w += __shfl_xor(a.w, 16);
        a.x += __shfl_xor(a.x, 32); a.y += __shfl_xor(a.y, 32);
        a.z += __shfl_xor(a.z, 32); a.w += __shfl_xor(a.w, 32);

        if (lane < 16) {
            const float rdeg = 1.0f / fmaxf((float)(r1 - r0), 1.0f);
            const __half2 p0 = __floats2half2_rn(a.x * rdeg, a.y * rdeg);
            const __half2 p1 = __floats2half2_rn(a.z * rdeg, a.w * rdeg);
            uint2 o = make_uint2(__builtin_bit_cast(unsigned, p0),
                                 __builtin_bit_cast(unsigned, p1));
            ((uint2*)m)[(size_t)node * 16 + gl] = o;
        }
    }
}

// ---------------------------------------------------------------------------
// MFMA SAGE transform: h = ELU(m@Wa + ba + res@Wb) for 16 nodes per wave.
// A-frag (nodes x K): lane l holds node l&15, k = (l>>4)*8 + [0..7] -> one
// 16B row-segment load per K-step. B-frags prepacked (pack_wb). C/D layout
// (guide-verified, m89/m91): col = lane&15, row(node) = (lane>>4)*4 + reg.
// 16 MFMAs per 16 nodes replace ~2500 VALU ops of the dot2 path (53us).
// hout == res in place is safe: wave reads then writes only its own 16 rows.
// ---------------------------------------------------------------------------
__global__ __launch_bounds__(256)
void mm_layer_kernel(const __half* __restrict__ mh,
                     const __half* __restrict__ res,
                     const __half* __restrict__ wA,   // lin_l packed B-frags
                     const float* __restrict__ ba,
                     const __half* __restrict__ wB,   // lin_r packed B-frags
                     __half* __restrict__ hout,
                     int n) {
    const int lane = threadIdx.x & 63;
    const int wave = threadIdx.x >> 6;
    const int g = blockIdx.x * 4 + wave;      // 16-node group
    const int node0 = g * 16;
    if (node0 >= n) return;
    const int li = lane & 15, hi = lane >> 4;

    const int nodeA = min(node0 + li, n - 1);
    const f16x8 am0 = *(const f16x8*)&mh[(size_t)nodeA * D + hi * 8];
    const f16x8 am1 = *(const f16x8*)&mh[(size_t)nodeA * D + 32 + hi * 8];
    const f16x8 ax0 = *(const f16x8*)&res[(size_t)nodeA * D + hi * 8];
    const f16x8 ax1 = *(const f16x8*)&res[(size_t)nodeA * D + 32 + hi * 8];

#pragma unroll
    for (int c = 0; c < 4; ++c) {
        const f16x8 bA0 = *(const f16x8*)&wA[((c * 2 + 0) * 64 + lane) * 8];
        const f16x8 bA1 = *(const f16x8*)&wA[((c * 2 + 1) * 64 + lane) * 8];
        const f16x8 bB0 = *(const f16x8*)&wB[((c * 2 + 0) * 64 + lane) * 8];
        const f16x8 bB1 = *(const f16x8*)&wB[((c * 2 + 1) * 64 + lane) * 8];
        const float bv = ba[c * 16 + li];
        f32x4 acc = {bv, bv, bv, bv};
        acc = __builtin_amdgcn_mfma_f32_16x16x32_f16(am0, bA0, acc, 0, 0, 0);
        acc = __builtin_amdgcn_mfma_f32_16x16x32_f16(am1, bA1, acc, 0, 0, 0);
        acc = __builtin_amdgcn_mfma_f32_16x16x32_f16(ax0, bB0, acc, 0, 0, 0);
        acc = __builtin_amdgcn_mfma_f32_16x16x32_f16(ax1, bB1, acc, 0, 0, 0);
#pragma unroll
        for (int r = 0; r < 4; ++r) {
            float v = acc[r];
            v = v > 0.0f ? v : expm1f(v);   // ELU(alpha=1)
            const float vp = __shfl_xor(v, 1);
            const int noder = node0 + hi * 4 + r;
            if (!(lane & 1) && noder < n) {
                const __half2 p = __floats2half2_rn(v, vp);
                *(__half2*)&hout[(size_t)noder * D + c * 16 + li] = p;
            }
        }
    }
}

// ---------------------------------------------------------------------------
// MFMA final linear: out = h@Wlin + blin (f32 output). Same structure.
// ---------------------------------------------------------------------------
__global__ __launch_bounds__(256)
void mm_final_kernel(const __half* __restrict__ h,
                     const __half* __restrict__ wF,
                     const float* __restrict__ bias,
                     float* __restrict__ out,
                     int n) {
    const int lane = threadIdx.x & 63;
    const int wave = threadIdx.x >> 6;
    const int g = blockIdx.x * 4 + wave;
    const int node0 = g * 16;
    if (node0 >= n) return;
    const int li = lane & 15, hi = lane >> 4;

    const int nodeA = min(node0 + li, n - 1);
    const f16x8 ah0 = *(const f16x8*)&h[(size_t)nodeA * D + hi * 8];
    const f16x8 ah1 = *(const f16x8*)&h[(size_t)nodeA * D + 32 + hi * 8];

#pragma unroll
    for (int c = 0; c < 4; ++c) {
        const f16x8 b0 = *(const f16x8*)&wF[((c * 2 + 0) * 64 + lane) * 8];
        const f16x8 b1 = *(const f16x8*)&wF[((c * 2 + 1) * 64 + lane) * 8];
        const float bv = bias[c * 16 + li];
        f32x4 acc = {bv, bv, bv, bv};
        acc = __builtin_amdgcn_mfma_f32_16x16x32_f16(ah0, b0, acc, 0, 0, 0);
        acc = __builtin_amdgcn_mfma_f32_16x16x32_f16(ah1, b1, acc, 0, 0, 0);
#pragma unroll
        for (int r = 0; r < 4; ++r) {
            const int noder = node0 + hi * 4 + r;
            if (noder < n)
                out[(size_t)noder * D + c * 16 + li] = acc[r];
        }
    }
}

extern "C" void kernel_launch(void* const* d_in, const int* in_sizes, int n_in,
                              void* d_out, int out_size, void* d_ws, size_t ws_size,
                              hipStream_t stream) {
    const float* x    = (const float*)d_in[0];
    const int*   ei   = (const int*)d_in[1];
    const float* W1l  = (const float*)d_in[2];
    const float* b1   = (const float*)d_in[3];
    const float* W1r  = (const float*)d_in[4];
    const float* W2l  = (const float*)d_in[5];
    const float* b2   = (const float*)d_in[6];
    const float* W2r  = (const float*)d_in[7];
    const float* Wlin = (const float*)d_in[8];
    const float* blin = (const float*)d_in[9];

    const int N_ = in_sizes[0] / D;      // 100000
    const int E_ = in_sizes[1] / 2;      // 1600000
    const int* src = ei;
    const int* dst = ei + E_;

    // workspace layout
    int* bcnt     = (int*)d_ws;                     // MAXBUCK
    int* bbase    = bcnt + MAXBUCK;                 // MAXBUCK+1
    int* cursor   = bbase + MAXBUCK + 1;            // MAXBUCK
    int* rowStart = cursor + MAXBUCK;               // N+1
    unsigned* pairs = (unsigned*)(rowStart + N_ + 1);// E (packed src<<7|dloc)
    int* csr      = (int*)(pairs + E_);             // E
    // align fp16 region to 64 B for f16x8 (16 B) vector loads
    uintptr_t pa = (uintptr_t)(csr + E_);
    pa = (pa + 63) & ~(uintptr_t)63;
    __half* wBbuf = (__half*)pa;                    // 5*4096 halves (40 KB)
    __half* mh    = wBbuf + 5 * 4096;               // N*64 halves (mean)
    __half* fh    = mh + (size_t)N_ * D;            // N*64 halves (x -> h1 -> h2)

    const __half* wb1l  = wBbuf;
    const __half* wb1r  = wBbuf + 4096;
    const __half* wb2l  = wBbuf + 8192;
    const __half* wb2r  = wBbuf + 12288;
    const __half* wblin = wBbuf + 16384;

    const int nbuck = (N_ + BNODES - 1) >> BSHIFT;          // 782
    const int npart = (E_ + PA_EDGES - 1) / PA_EDGES;       // 391
    const int ngrp  = (N_ + 15) / 16;                       // 6250
    const int gmm   = (ngrp + 3) / 4;                       // blocks for mm kernels

    hipMemsetAsync(bcnt, 0, (size_t)MAXBUCK * sizeof(int), stream);

    bhist_kernel<<<npart, 256, 0, stream>>>(dst, bcnt, E_, nbuck);
    bucket_scan_kernel<<<1, 256, 0, stream>>>(bcnt, bbase, cursor, nbuck, E_);
    partition_kernel<<<npart, 256, 0, stream>>>(src, dst, cursor, pairs, E_, nbuck);
    bucket_fill_kernel<<<nbuck, 256, 0, stream>>>(pairs, bbase, rowStart, csr, N_, E_);
    cast_half_kernel<<<1024, 256, 0, stream>>>(x, fh, N_ * D / 2);
    pack_wb_kernel<<<(5 * 4096 + 255) / 256, 256, 0, stream>>>(
        W1l, W1r, W2l, W2r, Wlin, wBbuf);

    // Layer 1: m1 = mean(xh[nbrs]) ; h1 = ELU(m1@W1l + b1 + x@W1r)  -> fh (fp16)
    aggmean_kernel<<<2048, 256, 0, stream>>>(fh, rowStart, csr, mh, N_);
    mm_layer_kernel<<<gmm, 256, 0, stream>>>(mh, fh, wb1l, b1, wb1r, fh, N_);
    // Layer 2: m2 = mean(h1[nbrs]) ; h2 = ELU(m2@W2l + b2 + h1@W2r)  -> fh (fp16)
    aggmean_kernel<<<2048, 256, 0, stream>>>(fh, rowStart, csr, mh, N_);
    mm_layer_kernel<<<gmm, 256, 0, stream>>>(mh, fh, wb2l, b2, wb2r, fh, N_);
    // Final: out = h2@Wlin + blin  (f32)
    mm_final_kernel<<<gmm, 256, 0, stream>>>(fh, wblin, blin, (float*)d_out, N_);
}

// Round 14
// 201.225 us; speedup vs baseline: 1.4435x; 1.0387x over previous
//
#include <hip/hip_runtime.h>
#include <hip/hip_fp16.h>
#include <cmath>

#define D 64
#define PA_EDGES 4096     // edges per partition/bhist block
#define BSHIFT 7          // bucket = 128 nodes
#define BNODES 128
#define MAXBUCK 1024      // supports N <= 131072
#define PB_CAP 4096       // LDS csr staging per bucket (avg 2048, ~45 sigma)

typedef _Float16 f16x8 __attribute__((ext_vector_type(8)));
typedef float f32x4 __attribute__((ext_vector_type(4)));

// ---------------------------------------------------------------------------
// Per-BUCKET histogram, LDS-privatized.
// ---------------------------------------------------------------------------
__global__ __launch_bounds__(256)
void bhist_kernel(const int* __restrict__ dst, int* __restrict__ bcnt, int E, int nbuck) {
    __shared__ int lh[MAXBUCK];
    const int t = threadIdx.x;
    const int e0 = blockIdx.x * PA_EDGES;
    const int ecnt = min(PA_EDGES, E - e0);
    for (int i = t; i < MAXBUCK; i += 256) lh[i] = 0;
    __syncthreads();
    for (int i = t; i < ecnt; i += 256) atomicAdd(&lh[dst[e0 + i] >> BSHIFT], 1);
    __syncthreads();
    for (int b = t; b < nbuck; b += 256) {
        const int c = lh[b];
        if (c) atomicAdd(&bcnt[b], c);
    }
}

// ---------------------------------------------------------------------------
// Exclusive scan of bucket counts -> bbase (and cursor copy). One block.
// ---------------------------------------------------------------------------
__global__ __launch_bounds__(256)
void bucket_scan_kernel(const int* __restrict__ bcnt, int* __restrict__ bbase,
                        int* __restrict__ cursor, int nbuck, int E) {
    __shared__ int red[256];
    const int t = threadIdx.x;
    const int c0 = (4 * t + 0 < nbuck) ? bcnt[4 * t + 0] : 0;
    const int c1 = (4 * t + 1 < nbuck) ? bcnt[4 * t + 1] : 0;
    const int c2 = (4 * t + 2 < nbuck) ? bcnt[4 * t + 2] : 0;
    const int c3 = (4 * t + 3 < nbuck) ? bcnt[4 * t + 3] : 0;
    red[t] = c0 + c1 + c2 + c3;
    __syncthreads();
    for (int off = 1; off < 256; off <<= 1) {
        int u = (t >= off) ? red[t - off] : 0;
        __syncthreads();
        red[t] += u;
        __syncthreads();
    }
    const int excl = (t == 0) ? 0 : red[t - 1];
    const int e0 = excl, e1 = excl + c0, e2 = excl + c0 + c1, e3 = excl + c0 + c1 + c2;
    if (4 * t + 0 <= nbuck) { bbase[4 * t + 0] = e0; }
    if (4 * t + 1 <= nbuck) { bbase[4 * t + 1] = e1; }
    if (4 * t + 2 <= nbuck) { bbase[4 * t + 2] = e2; }
    if (4 * t + 3 <= nbuck) { bbase[4 * t + 3] = e3; }
    if (4 * t + 0 < nbuck) cursor[4 * t + 0] = e0;
    if (4 * t + 1 < nbuck) cursor[4 * t + 1] = e1;
    if (4 * t + 2 < nbuck) cursor[4 * t + 2] = e2;
    if (4 * t + 3 < nbuck) cursor[4 * t + 3] = e3;
    if (t == 255) bbase[nbuck] = E;   // total (exclusive scan end)
}

// ---------------------------------------------------------------------------
// Bucket partition: (src, dst) -> packed 32-bit (src<<7 | dst&127), grouped
// by bucket (dst>>7) in `pairs`. LDS-staged; int LDS atomics only (native
// ds_add_u32 -- float LDS atomics are CAS loops on HIP, never use them).
// ---------------------------------------------------------------------------
__global__ __launch_bounds__(256)
void partition_kernel(const int* __restrict__ src, const int* __restrict__ dst,
                      int* __restrict__ cursor, unsigned* __restrict__ pairs,
                      int E, int nbuck) {
    __shared__ int lhist[MAXBUCK];            // counts, then local fill cursors
    __shared__ int lbase[MAXBUCK];            // local exclusive scan
    __shared__ int gbase[MAXBUCK];            // reserved global positions
    __shared__ int red[256];
    __shared__ unsigned stage[PA_EDGES];      // 16 KB
    __shared__ unsigned short sbuck[PA_EDGES];// 8 KB bucket id per staged slot

    const int t = threadIdx.x;
    const int e0 = blockIdx.x * PA_EDGES;
    const int ecnt = min(PA_EDGES, E - e0);

    for (int i = t; i < MAXBUCK; i += 256) lhist[i] = 0;
    __syncthreads();
    for (int i = t; i < ecnt; i += 256) atomicAdd(&lhist[dst[e0 + i] >> BSHIFT], 1);
    __syncthreads();

    // exclusive scan over 1024 entries: each thread owns 4 consecutive slots
    const int c0 = lhist[4 * t], c1 = lhist[4 * t + 1];
    const int c2 = lhist[4 * t + 2], c3 = lhist[4 * t + 3];
    red[t] = c0 + c1 + c2 + c3;
    __syncthreads();
    for (int off = 1; off < 256; off <<= 1) {
        int u = (t >= off) ? red[t - off] : 0;
        __syncthreads();
        red[t] += u;
        __syncthreads();
    }
    const int excl = (t == 0) ? 0 : red[t - 1];
    lbase[4 * t]     = excl;
    lbase[4 * t + 1] = excl + c0;
    lbase[4 * t + 2] = excl + c0 + c1;
    lbase[4 * t + 3] = excl + c0 + c1 + c2;
    for (int b = t; b < nbuck; b += 256) {
        const int c = lhist[b];
        gbase[b] = c ? atomicAdd(&cursor[b], c) : 0;
    }
    __syncthreads();
    for (int i = t; i < MAXBUCK; i += 256) lhist[i] = 0;   // reuse as fill cursors
    __syncthreads();
    for (int i = t; i < ecnt; i += 256) {
        const int d = dst[e0 + i];
        const int b = d >> BSHIFT;
        const int p = lbase[b] + atomicAdd(&lhist[b], 1);
        stage[p] = ((unsigned)src[e0 + i] << BSHIFT) | (unsigned)(d & (BNODES - 1));
        sbuck[p] = (unsigned short)b;
    }
    __syncthreads();
    for (int i = t; i < ecnt; i += 256) {
        const int b = sbuck[i];
        pairs[gbase[b] + (i - lbase[b])] = stage[i];
    }
}

// ---------------------------------------------------------------------------
// Bucket CSR fill + per-node rowStart derivation, fully on-chip.
// ---------------------------------------------------------------------------
__global__ __launch_bounds__(256)
void bucket_fill_kernel(const unsigned* __restrict__ pairs, const int* __restrict__ bbase,
                        int* __restrict__ rowStart, int* __restrict__ csr, int n, int E) {
    __shared__ int lcsr[PB_CAP];          // 16 KB
    __shared__ int lcnt[BNODES];          // per-node degree
    __shared__ int lrs[BNODES];           // per-node row start (bucket-relative)
    __shared__ int s[BNODES];             // scan workspace
    __shared__ int lfill[BNODES];
    const int t = threadIdx.x;
    const int node0 = blockIdx.x << BSHIFT;
    const int bn = min(BNODES, n - node0);
    const int base = bbase[blockIdx.x];
    const int cntE = bbase[blockIdx.x + 1] - base;

    if (t < BNODES) { lcnt[t] = 0; lfill[t] = 0; }
    __syncthreads();
    for (int i = t; i < cntE; i += 256)
        atomicAdd(&lcnt[pairs[base + i] & (BNODES - 1)], 1);
    __syncthreads();
    if (t < BNODES) s[t] = lcnt[t];
    __syncthreads();
    for (int off = 1; off < BNODES; off <<= 1) {
        int u = (t >= off && t < BNODES) ? s[t - off] : 0;
        __syncthreads();
        if (t < BNODES) s[t] += u;
        __syncthreads();
    }
    if (t < BNODES) lrs[t] = (t == 0) ? 0 : s[t - 1];
    __syncthreads();
    if (t < bn) rowStart[node0 + t] = base + lrs[t];
    if (blockIdx.x == gridDim.x - 1 && t == 0) rowStart[n] = E;

    if (cntE <= PB_CAP) {
        for (int i = t; i < cntE; i += 256) {
            const unsigned pr = pairs[base + i];
            const int dl = (int)(pr & (BNODES - 1));
            const int p = lrs[dl] + atomicAdd(&lfill[dl], 1);
            lcsr[p] = (int)(pr >> BSHIFT);
        }
        __syncthreads();
        for (int i = t; i < cntE; i += 256) csr[base + i] = lcsr[i];
    } else {   // safety fallback (statistically unreachable for random dst)
        for (int i = t; i < cntE; i += 256) {
            const unsigned pr = pairs[base + i];
            const int dl = (int)(pr & (BNODES - 1));
            const int p = base + lrs[dl] + atomicAdd(&lfill[dl], 1);
            csr[p] = (int)(pr >> BSHIFT);
        }
    }
}

// ---------------------------------------------------------------------------
// Fused f32->f16 cast (grid-stride) + MFMA weight-fragment pack (first
// 20480 threads). Pack layout: wB[mat][((c*2+kk)*64 + lane)*8 + e] =
// W[kk*32 + (lane>>4)*8 + e][c*16 + (lane&15)] -- one 16B lane-load gives a
// ready B-fragment for col-tile c, K-step kk.
// ---------------------------------------------------------------------------
__global__ __launch_bounds__(256)
void cast_pack_kernel(const float* __restrict__ in, __half* __restrict__ out, int n2,
                      const float* __restrict__ W1l, const float* __restrict__ W1r,
                      const float* __restrict__ W2l, const float* __restrict__ W2r,
                      const float* __restrict__ Wlin, __half* __restrict__ wB) {
    const int gid = blockIdx.x * 256 + threadIdx.x;
    if (gid < 5 * 4096) {
        const int mat = gid >> 12;
        const float* W = (mat == 0) ? W1l : (mat == 1) ? W1r : (mat == 2) ? W2l
                        : (mat == 3) ? W2r : Wlin;
        const int r = gid & 4095;
        const int e = r & 7;
        const int ln = (r >> 3) & 63;
        const int kk = (r >> 9) & 1;
        const int c = r >> 10;
        const int k = kk * 32 + ((ln >> 4) << 3) + e;
        const int col = c * 16 + (ln & 15);
        wB[gid] = __float2half_rn(W[k * D + col]);
    }
    const float2* in2 = (const float2*)in;
    __half2* out2 = (__half2*)out;
    const int st = gridDim.x * 256;
    for (int i = gid; i < n2; i += st) {
        const float2 v = in2[i];
        out2[i] = __floats2half2_rn(v.x, v.y);
    }
}

// ---------------------------------------------------------------------------
// Gather-mean from the fp16 feature copy; output packed fp16 row-major.
// REGISTER-LEAN (VGPR 20, 70% occupancy) -- R11 proved fusing compute here
// collapses occupancy and the ~3.3 TB/s random-gather throughput. At that
// BW this kernel is at the random-128B-fetch structural ceiling (R13 PMC:
// concurrency ample, BW-limited).
// ---------------------------------------------------------------------------
__device__ __forceinline__ void addh4(float4& a, const __half* __restrict__ p) {
    union { unsigned long long u; __half2 h[2]; } r;
    r.u = *(const unsigned long long*)p;       // 8 B load
    const float2 f0 = __half22float2(r.h[0]);
    const float2 f1 = __half22float2(r.h[1]);
    a.x += f0.x; a.y += f0.y; a.z += f1.x; a.w += f1.y;
}

__global__ __launch_bounds__(256)
void aggmean_kernel(const __half* __restrict__ xh, const int* __restrict__ rowStart,
                    const int* __restrict__ csr, __half* __restrict__ m, int n) {
    const int lane = threadIdx.x & 63;
    const int g = lane >> 4;              // group 0..3
    const int gl = lane & 15;             // lane in group
    const int wave = threadIdx.x >> 6;
    const int gw = blockIdx.x * 4 + wave;
    const int nw = gridDim.x * 4;

    for (int node = gw; node < n; node += nw) {
        const int r0 = rowStart[node];
        const int r1 = rowStart[node + 1];
        float4 acc0 = make_float4(0.f, 0.f, 0.f, 0.f);
        float4 acc1 = make_float4(0.f, 0.f, 0.f, 0.f);

        int j = r0;
        for (; j + 16 <= r1; j += 16) {
            const int i0 = csr[j + 0  + g];
            const int i1 = csr[j + 4  + g];
            const int i2 = csr[j + 8  + g];
            const int i3 = csr[j + 12 + g];
            addh4(acc0, &xh[(size_t)i0 * D + gl * 4]);
            addh4(acc1, &xh[(size_t)i1 * D + gl * 4]);
            addh4(acc0, &xh[(size_t)i2 * D + gl * 4]);
            addh4(acc1, &xh[(size_t)i3 * D + gl * 4]);
        }
        const int rem = r1 - j;
        if (rem > 0) {
            if (0 + g < rem) {
                const int sidx = csr[j + 0 + g];
                addh4(acc0, &xh[(size_t)sidx * D + gl * 4]);
            }
            if (4 + g < rem) {
                const int sidx = csr[j + 4 + g];
                addh4(acc1, &xh[(size_t)sidx * D + gl * 4]);
            }
            if (8 + g < rem) {
                const int sidx = csr[j + 8 + g];
                addh4(acc0, &xh[(size_t)sidx * D + gl * 4]);
            }
            if (12 + g < rem) {
                const int sidx = csr[j + 12 + g];
                addh4(acc1, &xh[(size_t)sidx * D + gl * 4]);
            }
        }

        float4 a;
        a.x = acc0.x + acc1.x; a.y = acc0.y + acc1.y;
        a.z = acc0.z + acc1.z; a.w = acc0.w + acc1.w;
        a.x += __shfl_xor(a.x, 16); a.y += __shfl_xor(a.y, 16);
        a.z += __shfl_xor(a.z, 16); a.w += __shfl_xor(a.w, 16);
        a.x += __shfl_xor(a.x, 32); a.y += __shfl_xor(a.y, 32);
        a.z += __shfl_xor(a.z, 32); a.w += __shfl_xor(a.w, 32);

        if (lane < 16) {
            const float rdeg = 1.0f / fmaxf((float)(r1 - r0), 1.0f);
            const __half2 p0 = __floats2half2_rn(a.x * rdeg, a.y * rdeg);
            const __half2 p1 = __floats2half2_rn(a.z * rdeg, a.w * rdeg);
            uint2 o = make_uint2(__builtin_bit_cast(unsigned, p0),
                                 __builtin_bit_cast(unsigned, p1));
            ((uint2*)m)[(size_t)node * 16 + gl] = o;
        }
    }
}

// ---------------------------------------------------------------------------
// MFMA SAGE transform: h = ELU(m@Wa + ba + res@Wb) for 16 nodes per wave.
// A-frag: lane l holds node l&15, k=(l>>4)*8+[0..7] (one 16B row-segment
// load per K-step). B-frags prepacked. C/D layout (guide-verified m89/m91):
// col = lane&15, row(node) = (lane>>4)*4 + reg.
// FINAL=false: write h packed fp16 (in place of res is safe: own rows only).
// FINAL=true: stage the wave's 16x64 h-tile in per-wave LDS (XOR-swizzled
// 16B blocks to break the 128B-stride bank conflict), read back as A-frags,
// chain out = h@WpF + blin (8 more MFMAs), write f32. No barriers needed:
// tile is wave-private, in-wave ds ordering via lgkmcnt. Deletes the
// separate mm_final pass (12.8 MB re-read + 25.6 MB write + launch).
// ---------------------------------------------------------------------------
template <bool FINAL>
__global__ __launch_bounds__(256)
void mm_layer_kernel(const __half* __restrict__ mh,
                     const __half* __restrict__ res,
                     const __half* __restrict__ wA,   // lin_l packed B-frags
                     const float* __restrict__ ba,
                     const __half* __restrict__ wB,   // lin_r packed B-frags
                     const __half* __restrict__ wF,   // Wlin packed (FINAL)
                     const float* __restrict__ bfin,  // blin (FINAL)
                     __half* __restrict__ hout,       // !FINAL
                     float* __restrict__ fout,        // FINAL
                     int n) {
    __shared__ __half lt[FINAL ? 4 * 16 * 64 : 4];   // 8 KB (FINAL), per-wave tiles
    const int lane = threadIdx.x & 63;
    const int wave = threadIdx.x >> 6;
    const int g = blockIdx.x * 4 + wave;      // 16-node group
    const int node0 = g * 16;
    if (node0 >= n) return;
    const int li = lane & 15, hi = lane >> 4;
    char* wtile = (char*)&lt[wave * 16 * 64];

    const int nodeA = min(node0 + li, n - 1);
    const f16x8 am0 = *(const f16x8*)&mh[(size_t)nodeA * D + hi * 8];
    const f16x8 am1 = *(const f16x8*)&mh[(size_t)nodeA * D + 32 + hi * 8];
    const f16x8 ax0 = *(const f16x8*)&res[(size_t)nodeA * D + hi * 8];
    const f16x8 ax1 = *(const f16x8*)&res[(size_t)nodeA * D + 32 + hi * 8];

#pragma unroll
    for (int c = 0; c < 4; ++c) {
        const f16x8 bA0 = *(const f16x8*)&wA[((c * 2 + 0) * 64 + lane) * 8];
        const f16x8 bA1 = *(const f16x8*)&wA[((c * 2 + 1) * 64 + lane) * 8];
        const f16x8 bB0 = *(const f16x8*)&wB[((c * 2 + 0) * 64 + lane) * 8];
        const f16x8 bB1 = *(const f16x8*)&wB[((c * 2 + 1) * 64 + lane) * 8];
        const float bv = ba[c * 16 + li];
        f32x4 acc = {bv, bv, bv, bv};
        acc = __builtin_amdgcn_mfma_f32_16x16x32_f16(am0, bA0, acc, 0, 0, 0);
        acc = __builtin_amdgcn_mfma_f32_16x16x32_f16(am1, bA1, acc, 0, 0, 0);
        acc = __builtin_amdgcn_mfma_f32_16x16x32_f16(ax0, bB0, acc, 0, 0, 0);
        acc = __builtin_amdgcn_mfma_f32_16x16x32_f16(ax1, bB1, acc, 0, 0, 0);
#pragma unroll
        for (int r = 0; r < 4; ++r) {
            float v = acc[r];
            v = v > 0.0f ? v : expm1f(v);   // ELU(alpha=1)
            const float vp = __shfl_xor(v, 1);
            if (!FINAL) {
                const int noder = node0 + hi * 4 + r;
                if (!(lane & 1) && noder < n) {
                    const __half2 p = __floats2half2_rn(v, vp);
                    *(__half2*)&hout[(size_t)noder * D + c * 16 + li] = p;
                }
            } else {
                if (!(lane & 1)) {
                    const int row = hi * 4 + r;
                    // 16B-block XOR swizzle: block ^= row&7  (bijective per row)
                    const int boff = (c * 32 + li * 2) ^ ((row & 7) << 4);
                    *(__half2*)(wtile + row * 128 + boff) = __floats2half2_rn(v, vp);
                }
            }
        }
    }

    if (FINAL) {
        // read h-tile back as A-frags: lane l -> row l&15, cols (l>>4)*8..+7
        const int row = li;
        const int sw = (row & 7);
        const f16x8 ah0 = *(const f16x8*)(wtile + row * 128 + ((hi ^ sw) << 4));
        const f16x8 ah1 = *(const f16x8*)(wtile + row * 128 + (((4 + hi) ^ sw) << 4));
#pragma unroll
        for (int c = 0; c < 4; ++c) {
            const f16x8 b0 = *(const f16x8*)&wF[((c * 2 + 0) * 64 + lane) * 8];
            const f16x8 b1 = *(const f16x8*)&wF[((c * 2 + 1) * 64 + lane) * 8];
            const float bv = bfin[c * 16 + li];
            f32x4 acc = {bv, bv, bv, bv};
            acc = __builtin_amdgcn_mfma_f32_16x16x32_f16(ah0, b0, acc, 0, 0, 0);
            acc = __builtin_amdgcn_mfma_f32_16x16x32_f16(ah1, b1, acc, 0, 0, 0);
#pragma unroll
            for (int r = 0; r < 4; ++r) {
                const int noder = node0 + hi * 4 + r;
                if (noder < n)
                    fout[(size_t)noder * D + c * 16 + li] = acc[r];
            }
        }
    }
}

extern "C" void kernel_launch(void* const* d_in, const int* in_sizes, int n_in,
                              void* d_out, int out_size, void* d_ws, size_t ws_size,
                              hipStream_t stream) {
    const float* x    = (const float*)d_in[0];
    const int*   ei   = (const int*)d_in[1];
    const float* W1l  = (const float*)d_in[2];
    const float* b1   = (const float*)d_in[3];
    const float* W1r  = (const float*)d_in[4];
    const float* W2l  = (const float*)d_in[5];
    const float* b2   = (const float*)d_in[6];
    const float* W2r  = (const float*)d_in[7];
    const float* Wlin = (const float*)d_in[8];
    const float* blin = (const float*)d_in[9];

    const int N_ = in_sizes[0] / D;      // 100000
    const int E_ = in_sizes[1] / 2;      // 1600000
    const int* src = ei;
    const int* dst = ei + E_;

    // workspace layout
    int* bcnt     = (int*)d_ws;                     // MAXBUCK
    int* bbase    = bcnt + MAXBUCK;                 // MAXBUCK+1
    int* cursor   = bbase + MAXBUCK + 1;            // MAXBUCK
    int* rowStart = cursor + MAXBUCK;               // N+1
    unsigned* pairs = (unsigned*)(rowStart + N_ + 1);// E (packed src<<7|dloc)
    int* csr      = (int*)(pairs + E_);             // E
    // align fp16 region to 64 B for f16x8 (16 B) vector loads
    uintptr_t pa = (uintptr_t)(csr + E_);
    pa = (pa + 63) & ~(uintptr_t)63;
    __half* wBbuf = (__half*)pa;                    // 5*4096 halves (40 KB)
    __half* mh    = wBbuf + 5 * 4096;               // N*64 halves (mean)
    __half* fh    = mh + (size_t)N_ * D;            // N*64 halves (x -> h1 -> h2)

    const __half* wb1l  = wBbuf;
    const __half* wb1r  = wBbuf + 4096;
    const __half* wb2l  = wBbuf + 8192;
    const __half* wb2r  = wBbuf + 12288;
    const __half* wblin = wBbuf + 16384;

    const int nbuck = (N_ + BNODES - 1) >> BSHIFT;          // 782
    const int npart = (E_ + PA_EDGES - 1) / PA_EDGES;       // 391
    const int ngrp  = (N_ + 15) / 16;                       // 6250
    const int gmm   = (ngrp + 3) / 4;                       // blocks for mm kernels

    hipMemsetAsync(bcnt, 0, (size_t)MAXBUCK * sizeof(int), stream);

    bhist_kernel<<<npart, 256, 0, stream>>>(dst, bcnt, E_, nbuck);
    bucket_scan_kernel<<<1, 256, 0, stream>>>(bcnt, bbase, cursor, nbuck, E_);
    partition_kernel<<<npart, 256, 0, stream>>>(src, dst, cursor, pairs, E_, nbuck);
    bucket_fill_kernel<<<nbuck, 256, 0, stream>>>(pairs, bbase, rowStart, csr, N_, E_);
    cast_pack_kernel<<<1024, 256, 0, stream>>>(x, fh, N_ * D / 2,
                                               W1l, W1r, W2l, W2r, Wlin, wBbuf);

    // Layer 1: m1 = mean(xh[nbrs]) ; h1 = ELU(m1@W1l + b1 + x@W1r)  -> fh (fp16)
    aggmean_kernel<<<2048, 256, 0, stream>>>(fh, rowStart, csr, mh, N_);
    mm_layer_kernel<false><<<gmm, 256, 0, stream>>>(
        mh, fh, wb1l, b1, wb1r, nullptr, nullptr, fh, nullptr, N_);
    // Layer 2 + final: out = ELU(m2@W2l + b2 + h1@W2r)@Wlin + blin  (f32)
    aggmean_kernel<<<2048, 256, 0, stream>>>(fh, rowStart, csr, mh, N_);
    mm_layer_kernel<true><<<gmm, 256, 0, stream>>>(
        mh, fh, wb2l, b2, wb2r, wblin, blin, nullptr, (float*)d_out, N_);
}